// Round 2
// baseline (1543.411 us; speedup 1.0000x reference)
//
#include <hip/hip_runtime.h>

// BiasedInterpretedFlockingModel
// pos (N,2) f32, vel (N,2) f32, edge_index (2,NE) int32 (harness narrows
// int64 -> int32) -> out (N,2) f32
//
// Edge phase: msg = f(pos[dst]-pos[src]); masked to 0 iff pos AND vel deltas
// are all exactly zero (only possible for effective self-loops -> lazy vel
// load). Scatter 4 msg sums + count into ws via HW fp32 atomics.
// Node phase: y0=sum(m2), y1=sum(m3), y2=mean(m0), y3=mean(m1) -> update net.

__global__ __launch_bounds__(256) void zero_ws_kernel(float* __restrict__ p, int n) {
    int i = blockIdx.x * blockDim.x + threadIdx.x;
    if (i < n) p[i] = 0.0f;
}

__global__ __launch_bounds__(256) void edge_kernel(
    const float2* __restrict__ pos,
    const float2* __restrict__ vel,
    const int* __restrict__ ei,   // [2][ne] int32
    float* __restrict__ a0,   // sum m2 -> y0
    float* __restrict__ a1,   // sum m3 -> y1
    float* __restrict__ a2,   // sum m0 -> y2*cnt
    float* __restrict__ a3,   // sum m1 -> y3*cnt
    float* __restrict__ cnt,
    int ne)
{
    int stride = gridDim.x * blockDim.x;
    for (int e = blockIdx.x * blockDim.x + threadIdx.x; e < ne; e += stride) {
        int s = ei[e];        // src
        int d = ei[ne + e];   // dst
        float2 ps = pos[s];
        float2 pd = pos[d];
        float x0 = pd.x - ps.x;
        float x1 = pd.y - ps.y;

        // zero_mask: ALL of (dpos, dvel) exactly zero. Only check vel when
        // dpos is already zero (rare), to skip 2 gathers/edge.
        bool zmask = false;
        if (x0 == 0.0f && x1 == 0.0f) {
            float2 vs = vel[s];
            float2 vd = vel[d];
            zmask = (vd.x == vs.x) && (vd.y == vs.y);
        }

        // count includes masked edges (reference counts ALL edges)
        unsafeAtomicAdd(&cnt[d], 1.0f);

        if (!zmask) {
            float t0 = x0 * 0.07104663f;
            float m0 = (x0 - x1 / (t0 * t0 + 1.536996f)) * -0.028956918f;
            float t1 = x0 * -0.021992652f;
            float m1 = (x0 - x1 * (0.8290067f - t1 * t1)) * 0.025425926f;
            float t2 = x0 * -0.083299406f;
            float m2 = (x0 - t2 * t2) * -0.024002103f - 0.22298379f;
            float m3 = (x1 + 2.6200492f + x0 * -0.16023761f) * 0.025031794f;
            unsafeAtomicAdd(&a0[d], m2);
            unsafeAtomicAdd(&a1[d], m3);
            unsafeAtomicAdd(&a2[d], m0);
            unsafeAtomicAdd(&a3[d], m1);
        }
    }
}

__global__ __launch_bounds__(256) void node_kernel(
    const float* __restrict__ a0,
    const float* __restrict__ a1,
    const float* __restrict__ a2,
    const float* __restrict__ a3,
    const float* __restrict__ cnt,
    float2* __restrict__ out,
    int n)
{
    int i = blockIdx.x * blockDim.x + threadIdx.x;
    if (i >= n) return;
    float y0 = a0[i];
    float y1 = a1[i];
    float c  = fmaxf(cnt[i], 1.0f);
    float y2 = a2[i] / c;
    float y3 = a3[i] / c;

    float t  = y2 * 0.15994334f;
    float u0 = (y0 - (y3 + t * t) / 1.7044706f - y2) * 0.16596459f;
    float s  = y2 * -0.089175865f;
    float u1 = (y1 - s * s * y3 - y2 + y3) * -0.05459863f;
    float u2 = (y3 + y0) * 0.05392959f;
    float u3 = y2 * (12.305774f / (y2 * y2 + 63.129406f));

    float p0 = ((u0 / 0.5268826f + u3 - u2) * -0.18549965f - (u1 + u2)) / 0.7328953f;
    float p1 = u0 * -0.8037861f - u1 + (u3 * 1.2175907f + u2);
    out[i] = make_float2(p0, p1);
}

extern "C" void kernel_launch(void* const* d_in, const int* in_sizes, int n_in,
                              void* d_out, int out_size, void* d_ws, size_t ws_size,
                              hipStream_t stream) {
    const float2* pos = (const float2*)d_in[0];
    const float2* vel = (const float2*)d_in[1];
    const int* ei = (const int*)d_in[2];
    int n  = in_sizes[0] / 2;   // 100000
    int ne = in_sizes[2] / 2;   // 6400000

    float* ws = (float*)d_ws;
    float* a0  = ws;
    float* a1  = ws + n;
    float* a2  = ws + 2 * (size_t)n;
    float* a3  = ws + 3 * (size_t)n;
    float* cnt = ws + 4 * (size_t)n;

    int zeroN = 5 * n;
    zero_ws_kernel<<<(zeroN + 255) / 256, 256, 0, stream>>>(ws, zeroN);

    int eblocks = (ne + 255) / 256;
    edge_kernel<<<eblocks, 256, 0, stream>>>(pos, vel, ei, a0, a1, a2, a3, cnt, ne);

    node_kernel<<<(n + 255) / 256, 256, 0, stream>>>(a0, a1, a2, a3, cnt,
                                                     (float2*)d_out, n);
}

// Round 3
// 352.097 us; speedup vs baseline: 4.3835x; 4.3835x over previous
//
#include <hip/hip_runtime.h>

// BiasedInterpretedFlockingModel — LDS-accumulation version.
// pos (N,2) f32, vel (N,2) f32, edge_index (2,NE) int32 -> out (N,2) f32
//
// R2 profile: 32M global fp32 atomics = 1.0 GB write-through to memory-side
// atomic point -> 1534us, atomic-throughput-bound. Fix: accumulate in LDS.
// Node space split into NRANGES ranges of NPR=8192 nodes (8192*5*4B = 160KiB
// = full LDS pool, 1 block/CU). Edges split into S slices. Block (slice,
// range) scans its slice, LDS-accumulates in-range edges, flushes a dense
// partial to ws with coalesced stores (no global atomics). reduce_node_kernel
// sums S partials and applies the update net.

#define NPR      8192
#define NRANGES  13          // ceil(100000 / 8192)

__device__ __forceinline__ void compute_msgs(float x0, float x1,
                                             float& m0, float& m1,
                                             float& m2, float& m3) {
    float t0 = x0 * 0.07104663f;
    m0 = (x0 - x1 / (t0 * t0 + 1.536996f)) * -0.028956918f;
    float t1 = x0 * -0.021992652f;
    m1 = (x0 - x1 * (0.8290067f - t1 * t1)) * 0.025425926f;
    float t2 = x0 * -0.083299406f;
    m2 = (x0 - t2 * t2) * -0.024002103f - 0.22298379f;
    m3 = (x1 + 2.6200492f + x0 * -0.16023761f) * 0.025031794f;
}

__device__ __forceinline__ void update_net(float y0, float y1, float y2, float y3,
                                           float& p0, float& p1) {
    float t  = y2 * 0.15994334f;
    float u0 = (y0 - (y3 + t * t) / 1.7044706f - y2) * 0.16596459f;
    float s  = y2 * -0.089175865f;
    float u1 = (y1 - s * s * y3 - y2 + y3) * -0.05459863f;
    float u2 = (y3 + y0) * 0.05392959f;
    float u3 = y2 * (12.305774f / (y2 * y2 + 63.129406f));
    p0 = ((u0 / 0.5268826f + u3 - u2) * -0.18549965f - (u1 + u2)) / 0.7328953f;
    p1 = u0 * -0.8037861f - u1 + (u3 * 1.2175907f + u2);
}

// ---------- fast path: LDS accumulation ----------

__global__ __launch_bounds__(1024) void edge_range_kernel(
    const float2* __restrict__ pos,
    const float2* __restrict__ vel,
    const int* __restrict__ ei,      // [2][ne]
    float* __restrict__ part,        // [S][NRANGES][5][NPR]
    int ne, int S)
{
    __shared__ float sm[5 * NPR];    // 160 KiB: planes {m2,m3,m0,m1,cnt}
    const int slice = blockIdx.x;
    const int range = blockIdx.y;
    const int base  = range * NPR;

    for (int i = threadIdx.x; i < 5 * NPR; i += blockDim.x) sm[i] = 0.0f;
    __syncthreads();

    const int lo = (int)((long long)ne * slice / S);
    const int hi = (int)((long long)ne * (slice + 1) / S);
    for (int e = lo + (int)threadIdx.x; e < hi; e += (int)blockDim.x) {
        int d = ei[ne + e];                       // dst
        unsigned local = (unsigned)(d - base);
        if (local < NPR) {
            int s = ei[e];                        // src
            float2 ps = pos[s];
            float2 pd = pos[d];
            float x0 = pd.x - ps.x;
            float x1 = pd.y - ps.y;

            bool zmask = false;
            if (x0 == 0.0f && x1 == 0.0f) {       // rare: lazy vel check
                float2 vs = vel[s];
                float2 vd = vel[d];
                zmask = (vd.x == vs.x) && (vd.y == vs.y);
            }

            atomicAdd(&sm[4 * NPR + local], 1.0f);   // count ALL edges
            if (!zmask) {
                float m0, m1, m2, m3;
                compute_msgs(x0, x1, m0, m1, m2, m3);
                atomicAdd(&sm[0 * NPR + local], m2);
                atomicAdd(&sm[1 * NPR + local], m3);
                atomicAdd(&sm[2 * NPR + local], m0);
                atomicAdd(&sm[3 * NPR + local], m1);
            }
        }
    }
    __syncthreads();

    float* dst = part + ((size_t)slice * NRANGES + range) * (5 * NPR);
    for (int i = threadIdx.x; i < 5 * NPR; i += blockDim.x) dst[i] = sm[i];
}

__global__ __launch_bounds__(256) void reduce_node_kernel(
    const float* __restrict__ part,  // [S][NRANGES][5][NPR]
    float2* __restrict__ out, int n, int S)
{
    int i = blockIdx.x * blockDim.x + threadIdx.x;
    if (i >= n) return;
    int r  = i >> 13;                // / NPR
    int li = i & (NPR - 1);

    float a0 = 0.f, a1 = 0.f, a2 = 0.f, a3 = 0.f, c = 0.f;
    const float* p = part + ((size_t)r * 5) * NPR + li;
    const size_t sstride = (size_t)NRANGES * 5 * NPR;
    for (int s = 0; s < S; ++s, p += sstride) {
        a0 += p[0 * NPR];
        a1 += p[1 * NPR];
        a2 += p[2 * NPR];
        a3 += p[3 * NPR];
        c  += p[4 * NPR];
    }
    float cm = fmaxf(c, 1.0f);
    float p0, p1;
    update_net(a0, a1, a2 / cm, a3 / cm, p0, p1);
    out[i] = make_float2(p0, p1);
}

// ---------- fallback path: global atomics (proven in R2) ----------

__global__ __launch_bounds__(256) void zero_ws_kernel(float* __restrict__ p, int n) {
    int i = blockIdx.x * blockDim.x + threadIdx.x;
    if (i < n) p[i] = 0.0f;
}

__global__ __launch_bounds__(256) void edge_atomic_kernel(
    const float2* __restrict__ pos, const float2* __restrict__ vel,
    const int* __restrict__ ei,
    float* __restrict__ a0, float* __restrict__ a1,
    float* __restrict__ a2, float* __restrict__ a3,
    float* __restrict__ cnt, int ne)
{
    int stride = gridDim.x * blockDim.x;
    for (int e = blockIdx.x * blockDim.x + threadIdx.x; e < ne; e += stride) {
        int s = ei[e];
        int d = ei[ne + e];
        float2 ps = pos[s];
        float2 pd = pos[d];
        float x0 = pd.x - ps.x;
        float x1 = pd.y - ps.y;
        bool zmask = false;
        if (x0 == 0.0f && x1 == 0.0f) {
            float2 vs = vel[s]; float2 vd = vel[d];
            zmask = (vd.x == vs.x) && (vd.y == vs.y);
        }
        unsafeAtomicAdd(&cnt[d], 1.0f);
        if (!zmask) {
            float m0, m1, m2, m3;
            compute_msgs(x0, x1, m0, m1, m2, m3);
            unsafeAtomicAdd(&a0[d], m2);
            unsafeAtomicAdd(&a1[d], m3);
            unsafeAtomicAdd(&a2[d], m0);
            unsafeAtomicAdd(&a3[d], m1);
        }
    }
}

__global__ __launch_bounds__(256) void node_kernel(
    const float* __restrict__ a0, const float* __restrict__ a1,
    const float* __restrict__ a2, const float* __restrict__ a3,
    const float* __restrict__ cnt, float2* __restrict__ out, int n)
{
    int i = blockIdx.x * blockDim.x + threadIdx.x;
    if (i >= n) return;
    float c = fmaxf(cnt[i], 1.0f);
    float p0, p1;
    update_net(a0[i], a1[i], a2[i] / c, a3[i] / c, p0, p1);
    out[i] = make_float2(p0, p1);
}

extern "C" void kernel_launch(void* const* d_in, const int* in_sizes, int n_in,
                              void* d_out, int out_size, void* d_ws, size_t ws_size,
                              hipStream_t stream) {
    const float2* pos = (const float2*)d_in[0];
    const float2* vel = (const float2*)d_in[1];
    const int* ei = (const int*)d_in[2];
    int n  = in_sizes[0] / 2;   // 100000
    int ne = in_sizes[2] / 2;   // 6400000

    const size_t per_slice = (size_t)NRANGES * 5 * NPR * sizeof(float); // ~2.13 MB

    if (n <= NRANGES * NPR && ws_size >= per_slice) {
        // fast path
        int S = (int)(ws_size / per_slice);
        if (S > 19) S = 19;                 // 13*19 = 247 blocks <= 256 CUs
        float* part = (float*)d_ws;
        dim3 grid(S, NRANGES);
        edge_range_kernel<<<grid, 1024, 0, stream>>>(pos, vel, ei, part, ne, S);
        reduce_node_kernel<<<(n + 255) / 256, 256, 0, stream>>>(part,
                                                 (float2*)d_out, n, S);
    } else {
        // fallback: R2 global-atomic path
        float* ws = (float*)d_ws;
        float* a0  = ws;
        float* a1  = ws + n;
        float* a2  = ws + 2 * (size_t)n;
        float* a3  = ws + 3 * (size_t)n;
        float* cnt = ws + 4 * (size_t)n;
        int zeroN = 5 * n;
        zero_ws_kernel<<<(zeroN + 255) / 256, 256, 0, stream>>>(ws, zeroN);
        edge_atomic_kernel<<<(ne + 255) / 256, 256, 0, stream>>>(pos, vel, ei,
                                                a0, a1, a2, a3, cnt, ne);
        node_kernel<<<(n + 255) / 256, 256, 0, stream>>>(a0, a1, a2, a3, cnt,
                                                (float2*)d_out, n);
    }
}

// Round 4
// 317.114 us; speedup vs baseline: 4.8671x; 1.1103x over previous
//
#include <hip/hip_runtime.h>

// BiasedInterpretedFlockingModel — binned two-phase version.
// pos (N,2) f32, vel (N,2) f32, edge_index (2,NE) int32 -> out (N,2) f32
//
// R3 was 13x-rescan + 1/13 lane hit rate (divergence/latency-bound, 352us).
// Now: count -> scan -> fill (bin edge ids by dst>>13) -> accum (dense
// buckets, 100% lane utilization, LDS planes, no global atomics) -> reduce.

#define NPR     8192
#define LOG2NPR 13
#define MAXR    13
#define NB      256
#define TPB     1024

__device__ __forceinline__ void compute_msgs(float x0, float x1,
                                             float& m0, float& m1,
                                             float& m2, float& m3) {
    float t0 = x0 * 0.07104663f;
    m0 = (x0 - x1 / (t0 * t0 + 1.536996f)) * -0.028956918f;
    float t1 = x0 * -0.021992652f;
    m1 = (x0 - x1 * (0.8290067f - t1 * t1)) * 0.025425926f;
    float t2 = x0 * -0.083299406f;
    m2 = (x0 - t2 * t2) * -0.024002103f - 0.22298379f;
    m3 = (x1 + 2.6200492f + x0 * -0.16023761f) * 0.025031794f;
}

__device__ __forceinline__ void update_net(float y0, float y1, float y2, float y3,
                                           float& p0, float& p1) {
    float t  = y2 * 0.15994334f;
    float u0 = (y0 - (y3 + t * t) / 1.7044706f - y2) * 0.16596459f;
    float s  = y2 * -0.089175865f;
    float u1 = (y1 - s * s * y3 - y2 + y3) * -0.05459863f;
    float u2 = (y3 + y0) * 0.05392959f;
    float u3 = y2 * (12.305774f / (y2 * y2 + 63.129406f));
    p0 = ((u0 / 0.5268826f + u3 - u2) * -0.18549965f - (u1 + u2)) / 0.7328953f;
    p1 = u0 * -0.8037861f - u1 + (u3 * 1.2175907f + u2);
}

// ---- phase 0: per-(block,range) histogram of dst ----
__global__ __launch_bounds__(TPB) void count_kernel(
    const int* __restrict__ dsts, int ne, int* __restrict__ cnts /*[NB][MAXR]*/)
{
    __shared__ int h[MAXR];
    if (threadIdx.x < MAXR) h[threadIdx.x] = 0;
    __syncthreads();
    const int b  = blockIdx.x;
    const int lo = (int)(((long long)ne * b / NB) & ~3LL);
    const int hi = (b == NB - 1) ? ne : (int)(((long long)ne * (b + 1) / NB) & ~3LL);
    const int hi4 = hi & ~3;

    int c[MAXR];
#pragma unroll
    for (int rr = 0; rr < MAXR; ++rr) c[rr] = 0;

    const int4* d4 = (const int4*)dsts;
    for (int i = lo / 4 + (int)threadIdx.x; 4 * i + 3 < hi; i += TPB) {
        int4 v = d4[i];
        int r0 = v.x >> LOG2NPR, r1 = v.y >> LOG2NPR;
        int r2 = v.z >> LOG2NPR, r3 = v.w >> LOG2NPR;
#pragma unroll
        for (int rr = 0; rr < MAXR; ++rr)
            c[rr] += (r0 == rr) + (r1 == rr) + (r2 == rr) + (r3 == rr);
    }
    for (int e = hi4 + (int)threadIdx.x; e < hi; e += TPB) {   // tail (empty if ne%4==0)
        int r = dsts[e] >> LOG2NPR;
#pragma unroll
        for (int rr = 0; rr < MAXR; ++rr) c[rr] += (r == rr);
    }
#pragma unroll
    for (int rr = 0; rr < MAXR; ++rr) {
#pragma unroll
        for (int off = 32; off; off >>= 1) c[rr] += __shfl_down(c[rr], off, 64);
    }
    if ((threadIdx.x & 63) == 0) {
#pragma unroll
        for (int rr = 0; rr < MAXR; ++rr) if (c[rr]) atomicAdd(&h[rr], c[rr]);
    }
    __syncthreads();
    if (threadIdx.x < MAXR) cnts[b * MAXR + (int)threadIdx.x] = h[threadIdx.x];
}

// ---- phase 0.5: exclusive prefix -> per-(block,range) write offsets ----
__global__ __launch_bounds__(TPB) void scan_kernel(
    const int* __restrict__ cnts, int* __restrict__ offs,
    int* __restrict__ meta /* [0,MAXR)=base, [MAXR,2*MAXR)=total */, int nranges)
{
    __shared__ int sh[NB * MAXR];
    __shared__ int tot[MAXR], bas[MAXR];
    for (int i = threadIdx.x; i < NB * MAXR; i += TPB) sh[i] = cnts[i];
    __syncthreads();
    if (threadIdx.x < (unsigned)nranges) {
        int r = threadIdx.x, run = 0;
        for (int b = 0; b < NB; ++b) {
            int v = sh[b * MAXR + r];
            sh[b * MAXR + r] = run;
            run += v;
        }
        tot[r] = run;
    }
    __syncthreads();
    if (threadIdx.x == 0) {
        int acc = 0;
        for (int r = 0; r < nranges; ++r) { bas[r] = acc; acc += tot[r]; }
    }
    __syncthreads();
    for (int i = threadIdx.x; i < NB * MAXR; i += TPB) {
        int r = i % MAXR;
        if (r < nranges) offs[i] = sh[i] + bas[r];
    }
    if (threadIdx.x < (unsigned)nranges) {
        meta[threadIdx.x] = bas[threadIdx.x];
        meta[MAXR + threadIdx.x] = tot[threadIdx.x];
    }
}

// ---- phase 1: write edge ids into range buckets (wave-aggregated) ----
__global__ __launch_bounds__(TPB) void fill_kernel(
    const int* __restrict__ dsts, int ne, int nranges,
    const int* __restrict__ offs, int* __restrict__ rec)
{
    __shared__ int cur[MAXR];
    const int b = blockIdx.x;
    if (threadIdx.x < (unsigned)nranges)
        cur[threadIdx.x] = offs[b * MAXR + (int)threadIdx.x];
    __syncthreads();
    const int lo = (int)(((long long)ne * b / NB) & ~3LL);
    const int hi = (b == NB - 1) ? ne : (int)(((long long)ne * (b + 1) / NB) & ~3LL);
    const int hi4 = hi & ~3;
    const int lane = (int)(threadIdx.x & 63);

    const int4* d4 = (const int4*)dsts;
    for (int i = lo / 4 + (int)threadIdx.x; 4 * i + 3 < hi; i += TPB) {
        int4 v = d4[i];
#pragma unroll
        for (int j = 0; j < 4; ++j) {
            int d = (j == 0) ? v.x : (j == 1) ? v.y : (j == 2) ? v.z : v.w;
            int e = 4 * i + j;
            int r = d >> LOG2NPR;
            for (int rr = 0; rr < nranges; ++rr) {
                unsigned long long m = __ballot(r == rr);
                if (!m) continue;
                int leader = (int)__builtin_ctzll(m);
                int base = 0;
                if (lane == leader) base = atomicAdd(&cur[rr], (int)__popcll(m));
                base = __shfl(base, leader, 64);
                if (r == rr) {
                    int rank = (int)__popcll(m & ((1ull << lane) - 1ull));
                    rec[base + rank] = e;
                }
            }
        }
    }
    for (int e = hi4 + (int)threadIdx.x; e < hi; e += TPB) {   // tail
        int r = dsts[e] >> LOG2NPR;
        for (int rr = 0; rr < nranges; ++rr) {
            unsigned long long m = __ballot(r == rr);
            if (!m) continue;
            int leader = (int)__builtin_ctzll(m);
            int base = 0;
            if (lane == leader) base = atomicAdd(&cur[rr], (int)__popcll(m));
            base = __shfl(base, leader, 64);
            if (r == rr) {
                int rank = (int)__popcll(m & ((1ull << lane) - 1ull));
                rec[base + rank] = e;
            }
        }
    }
}

// ---- phase 2: dense bucket accumulation in LDS ----
__global__ __launch_bounds__(TPB) void accum_kernel(
    const float2* __restrict__ pos, const float2* __restrict__ vel,
    const int* __restrict__ ei, int ne, int S,
    const int* __restrict__ rec, const int* __restrict__ meta,
    float* __restrict__ part)
{
    __shared__ float sm[5 * NPR];   // 160 KiB: {m2,m3,m0,m1,cnt}
    const int r  = blockIdx.x, si = blockIdx.y;
    const int base = meta[r];
    const int tot  = meta[MAXR + r];
    const int lo = base + (int)((long long)tot * si / S);
    const int hi = base + (int)((long long)tot * (si + 1) / S);
    const int nbase = r << LOG2NPR;

    for (int i = threadIdx.x; i < 5 * NPR; i += TPB) sm[i] = 0.0f;
    __syncthreads();

    for (int i = lo + (int)threadIdx.x; i < hi; i += TPB) {
        int e = rec[i];
        int s = ei[e];
        int d = ei[ne + e];
        int local = d - nbase;
        float2 ps = pos[s], pd = pos[d];
        float x0 = pd.x - ps.x;
        float x1 = pd.y - ps.y;
        bool zmask = false;
        if (x0 == 0.0f && x1 == 0.0f) {          // rare: lazy vel check
            float2 vs = vel[s], vd = vel[d];
            zmask = (vd.x == vs.x) && (vd.y == vs.y);
        }
        atomicAdd(&sm[4 * NPR + local], 1.0f);   // count ALL edges
        if (!zmask) {
            float m0, m1, m2, m3;
            compute_msgs(x0, x1, m0, m1, m2, m3);
            atomicAdd(&sm[0 * NPR + local], m2);
            atomicAdd(&sm[1 * NPR + local], m3);
            atomicAdd(&sm[2 * NPR + local], m0);
            atomicAdd(&sm[3 * NPR + local], m1);
        }
    }
    __syncthreads();
    float* dst = part + (size_t)(r * S + si) * (5 * NPR);
    for (int i = threadIdx.x; i < 5 * NPR; i += TPB) dst[i] = sm[i];
}

// ---- phase 3: fold S partials + update net ----
__global__ __launch_bounds__(256) void reduce_node_kernel(
    const float* __restrict__ part, float2* __restrict__ out, int n, int S)
{
    int i = blockIdx.x * blockDim.x + threadIdx.x;
    if (i >= n) return;
    int r  = i >> LOG2NPR;
    int li = i & (NPR - 1);
    float a0 = 0.f, a1 = 0.f, a2 = 0.f, a3 = 0.f, c = 0.f;
    const float* p = part + (size_t)(r * S) * (5 * NPR) + li;
    for (int s = 0; s < S; ++s, p += 5 * NPR) {
        a0 += p[0 * NPR];
        a1 += p[1 * NPR];
        a2 += p[2 * NPR];
        a3 += p[3 * NPR];
        c  += p[4 * NPR];
    }
    float cm = fmaxf(c, 1.0f);
    float p0, p1;
    update_net(a0, a1, a2 / cm, a3 / cm, p0, p1);
    out[i] = make_float2(p0, p1);
}

// ---- fallback path: global atomics (proven R2) ----
__global__ __launch_bounds__(256) void zero_ws_kernel(float* __restrict__ p, int n) {
    int i = blockIdx.x * blockDim.x + threadIdx.x;
    if (i < n) p[i] = 0.0f;
}

__global__ __launch_bounds__(256) void edge_atomic_kernel(
    const float2* __restrict__ pos, const float2* __restrict__ vel,
    const int* __restrict__ ei,
    float* __restrict__ a0, float* __restrict__ a1,
    float* __restrict__ a2, float* __restrict__ a3,
    float* __restrict__ cnt, int ne)
{
    int stride = gridDim.x * blockDim.x;
    for (int e = blockIdx.x * blockDim.x + threadIdx.x; e < ne; e += stride) {
        int s = ei[e];
        int d = ei[ne + e];
        float2 ps = pos[s], pd = pos[d];
        float x0 = pd.x - ps.x, x1 = pd.y - ps.y;
        bool zmask = false;
        if (x0 == 0.0f && x1 == 0.0f) {
            float2 vs = vel[s], vd = vel[d];
            zmask = (vd.x == vs.x) && (vd.y == vs.y);
        }
        unsafeAtomicAdd(&cnt[d], 1.0f);
        if (!zmask) {
            float m0, m1, m2, m3;
            compute_msgs(x0, x1, m0, m1, m2, m3);
            unsafeAtomicAdd(&a0[d], m2);
            unsafeAtomicAdd(&a1[d], m3);
            unsafeAtomicAdd(&a2[d], m0);
            unsafeAtomicAdd(&a3[d], m1);
        }
    }
}

__global__ __launch_bounds__(256) void node_kernel(
    const float* __restrict__ a0, const float* __restrict__ a1,
    const float* __restrict__ a2, const float* __restrict__ a3,
    const float* __restrict__ cnt, float2* __restrict__ out, int n)
{
    int i = blockIdx.x * blockDim.x + threadIdx.x;
    if (i >= n) return;
    float c = fmaxf(cnt[i], 1.0f);
    float p0, p1;
    update_net(a0[i], a1[i], a2[i] / c, a3[i] / c, p0, p1);
    out[i] = make_float2(p0, p1);
}

extern "C" void kernel_launch(void* const* d_in, const int* in_sizes, int n_in,
                              void* d_out, int out_size, void* d_ws, size_t ws_size,
                              hipStream_t stream) {
    const float2* pos = (const float2*)d_in[0];
    const float2* vel = (const float2*)d_in[1];
    const int* ei = (const int*)d_in[2];
    int n  = in_sizes[0] / 2;   // 100000
    int ne = in_sizes[2] / 2;   // 6400000

    int nranges = (n + NPR - 1) / NPR;
    size_t fixed    = ((size_t)NB * MAXR * 2 + 2 * MAXR + (size_t)ne) * sizeof(int);
    size_t per_part = (size_t)nranges * 5 * NPR * sizeof(float);   // ~2.13 MB

    int S = 0;
    if (nranges <= MAXR && ws_size > fixed)
        S = (int)((ws_size - fixed) / per_part);
    if (S > 16) S = 16;

    if (S >= 1) {
        int* cnts = (int*)d_ws;          // [NB][MAXR]
        int* offs = cnts + NB * MAXR;    // [NB][MAXR]
        int* meta = offs + NB * MAXR;    // base[MAXR], total[MAXR]
        int* rec  = meta + 2 * MAXR;     // [ne]
        float* part = (float*)(rec + ne);
        const int* dsts = ei + ne;

        count_kernel<<<NB, TPB, 0, stream>>>(dsts, ne, cnts);
        scan_kernel<<<1, TPB, 0, stream>>>(cnts, offs, meta, nranges);
        fill_kernel<<<NB, TPB, 0, stream>>>(dsts, ne, nranges, offs, rec);
        dim3 g(nranges, S);
        accum_kernel<<<g, TPB, 0, stream>>>(pos, vel, ei, ne, S, rec, meta, part);
        reduce_node_kernel<<<(n + 255) / 256, 256, 0, stream>>>(part,
                                                 (float2*)d_out, n, S);
    } else {
        float* ws = (float*)d_ws;
        float* a0  = ws;
        float* a1  = ws + n;
        float* a2  = ws + 2 * (size_t)n;
        float* a3  = ws + 3 * (size_t)n;
        float* cnt = ws + 4 * (size_t)n;
        int zeroN = 5 * n;
        zero_ws_kernel<<<(zeroN + 255) / 256, 256, 0, stream>>>(ws, zeroN);
        edge_atomic_kernel<<<(ne + 255) / 256, 256, 0, stream>>>(pos, vel, ei,
                                                a0, a1, a2, a3, cnt, ne);
        node_kernel<<<(n + 255) / 256, 256, 0, stream>>>(a0, a1, a2, a3, cnt,
                                                (float2*)d_out, n);
    }
}

// Round 5
// 283.600 us; speedup vs baseline: 5.4422x; 1.1182x over previous
//
#include <hip/hip_runtime.h>

// BiasedInterpretedFlockingModel — binned, payload-carrying version.
// pos (N,2) f32, vel (N,2) f32, edge_index (2,NE) int32 -> out (N,2) f32
//
// R4: accum was fetch-bound (386 MB) re-gathering ei[e]/ei[ne+e] in bucket
// order (13x line re-fetch). Now fill packs (local_dst<<17 | src) into the
// bucket entry itself; accum's only HBM stream is the coalesced rec read.
// Requires n <= 2^17 and nranges <= 13 (else fallback to global atomics).

#define NPR     8192
#define LOG2NPR 13
#define MAXR    13
#define NB      256
#define TPB     1024

__device__ __forceinline__ void compute_msgs(float x0, float x1,
                                             float& m0, float& m1,
                                             float& m2, float& m3) {
    float t0 = x0 * 0.07104663f;
    m0 = (x0 - x1 / (t0 * t0 + 1.536996f)) * -0.028956918f;
    float t1 = x0 * -0.021992652f;
    m1 = (x0 - x1 * (0.8290067f - t1 * t1)) * 0.025425926f;
    float t2 = x0 * -0.083299406f;
    m2 = (x0 - t2 * t2) * -0.024002103f - 0.22298379f;
    m3 = (x1 + 2.6200492f + x0 * -0.16023761f) * 0.025031794f;
}

__device__ __forceinline__ void update_net(float y0, float y1, float y2, float y3,
                                           float& p0, float& p1) {
    float t  = y2 * 0.15994334f;
    float u0 = (y0 - (y3 + t * t) / 1.7044706f - y2) * 0.16596459f;
    float s  = y2 * -0.089175865f;
    float u1 = (y1 - s * s * y3 - y2 + y3) * -0.05459863f;
    float u2 = (y3 + y0) * 0.05392959f;
    float u3 = y2 * (12.305774f / (y2 * y2 + 63.129406f));
    p0 = ((u0 / 0.5268826f + u3 - u2) * -0.18549965f - (u1 + u2)) / 0.7328953f;
    p1 = u0 * -0.8037861f - u1 + (u3 * 1.2175907f + u2);
}

// ---- phase 0: per-(block,range) histogram of dst ----
__global__ __launch_bounds__(TPB) void count_kernel(
    const int* __restrict__ dsts, int ne, int* __restrict__ cnts /*[NB][MAXR]*/)
{
    __shared__ int h[MAXR];
    if (threadIdx.x < MAXR) h[threadIdx.x] = 0;
    __syncthreads();
    const int b  = blockIdx.x;
    const int lo = (int)(((long long)ne * b / NB) & ~3LL);
    const int hi = (b == NB - 1) ? ne : (int)(((long long)ne * (b + 1) / NB) & ~3LL);
    const int hi4 = hi & ~3;

    int c[MAXR];
#pragma unroll
    for (int rr = 0; rr < MAXR; ++rr) c[rr] = 0;

    const int4* d4 = (const int4*)dsts;
    for (int i = lo / 4 + (int)threadIdx.x; 4 * i + 3 < hi; i += TPB) {
        int4 v = d4[i];
        int r0 = v.x >> LOG2NPR, r1 = v.y >> LOG2NPR;
        int r2 = v.z >> LOG2NPR, r3 = v.w >> LOG2NPR;
#pragma unroll
        for (int rr = 0; rr < MAXR; ++rr)
            c[rr] += (r0 == rr) + (r1 == rr) + (r2 == rr) + (r3 == rr);
    }
    for (int e = hi4 + (int)threadIdx.x; e < hi; e += TPB) {
        int r = dsts[e] >> LOG2NPR;
#pragma unroll
        for (int rr = 0; rr < MAXR; ++rr) c[rr] += (r == rr);
    }
#pragma unroll
    for (int rr = 0; rr < MAXR; ++rr) {
#pragma unroll
        for (int off = 32; off; off >>= 1) c[rr] += __shfl_down(c[rr], off, 64);
    }
    if ((threadIdx.x & 63) == 0) {
#pragma unroll
        for (int rr = 0; rr < MAXR; ++rr) if (c[rr]) atomicAdd(&h[rr], c[rr]);
    }
    __syncthreads();
    if (threadIdx.x < MAXR) cnts[b * MAXR + (int)threadIdx.x] = h[threadIdx.x];
}

// ---- phase 0.5: exclusive prefix -> per-(block,range) write offsets ----
__global__ __launch_bounds__(TPB) void scan_kernel(
    const int* __restrict__ cnts, int* __restrict__ offs,
    int* __restrict__ meta /* [0,MAXR)=base, [MAXR,2*MAXR)=total */, int nranges)
{
    __shared__ int sh[NB * MAXR];
    __shared__ int tot[MAXR], bas[MAXR];
    for (int i = threadIdx.x; i < NB * MAXR; i += TPB) sh[i] = cnts[i];
    __syncthreads();
    if (threadIdx.x < (unsigned)nranges) {
        int r = threadIdx.x, run = 0;
        for (int b = 0; b < NB; ++b) {
            int v = sh[b * MAXR + r];
            sh[b * MAXR + r] = run;
            run += v;
        }
        tot[r] = run;
    }
    __syncthreads();
    if (threadIdx.x == 0) {
        int acc = 0;
        for (int r = 0; r < nranges; ++r) { bas[r] = acc; acc += tot[r]; }
    }
    __syncthreads();
    for (int i = threadIdx.x; i < NB * MAXR; i += TPB) {
        int r = i % MAXR;
        if (r < nranges) offs[i] = sh[i] + bas[r];
    }
    if (threadIdx.x < (unsigned)nranges) {
        meta[threadIdx.x] = bas[threadIdx.x];
        meta[MAXR + threadIdx.x] = tot[threadIdx.x];
    }
}

// ---- phase 1: write packed (local<<17|src) into range buckets ----
__global__ __launch_bounds__(TPB) void fill_kernel(
    const int* __restrict__ srcs, const int* __restrict__ dsts, int ne, int nranges,
    const int* __restrict__ offs, unsigned* __restrict__ rec)
{
    __shared__ int cur[MAXR];
    const int b = blockIdx.x;
    if (threadIdx.x < (unsigned)nranges)
        cur[threadIdx.x] = offs[b * MAXR + (int)threadIdx.x];
    __syncthreads();
    const int lo = (int)(((long long)ne * b / NB) & ~3LL);
    const int hi = (b == NB - 1) ? ne : (int)(((long long)ne * (b + 1) / NB) & ~3LL);
    const int hi4 = hi & ~3;
    const int lane = (int)(threadIdx.x & 63);

    const int4* d4 = (const int4*)dsts;
    const int4* s4 = (const int4*)srcs;
    for (int i = lo / 4 + (int)threadIdx.x; 4 * i + 3 < hi; i += TPB) {
        int4 vd = d4[i];
        int4 vs = s4[i];
#pragma unroll
        for (int j = 0; j < 4; ++j) {
            int d = (j == 0) ? vd.x : (j == 1) ? vd.y : (j == 2) ? vd.z : vd.w;
            int s = (j == 0) ? vs.x : (j == 1) ? vs.y : (j == 2) ? vs.z : vs.w;
            int r = d >> LOG2NPR;
            unsigned p = ((unsigned)(d & (NPR - 1)) << 17) | (unsigned)s;
            for (int rr = 0; rr < nranges; ++rr) {
                unsigned long long m = __ballot(r == rr);
                if (!m) continue;
                int leader = (int)__builtin_ctzll(m);
                int base = 0;
                if (lane == leader) base = atomicAdd(&cur[rr], (int)__popcll(m));
                base = __shfl(base, leader, 64);
                if (r == rr) {
                    int rank = (int)__popcll(m & ((1ull << lane) - 1ull));
                    rec[base + rank] = p;
                }
            }
        }
    }
    for (int e = hi4 + (int)threadIdx.x; e < hi; e += TPB) {   // tail
        int d = dsts[e];
        int s = srcs[e];
        int r = d >> LOG2NPR;
        unsigned p = ((unsigned)(d & (NPR - 1)) << 17) | (unsigned)s;
        for (int rr = 0; rr < nranges; ++rr) {
            unsigned long long m = __ballot(r == rr);
            if (!m) continue;
            int leader = (int)__builtin_ctzll(m);
            int base = 0;
            if (lane == leader) base = atomicAdd(&cur[rr], (int)__popcll(m));
            base = __shfl(base, leader, 64);
            if (r == rr) {
                int rank = (int)__popcll(m & ((1ull << lane) - 1ull));
                rec[base + rank] = p;
            }
        }
    }
}

// ---- phase 2: dense bucket accumulation in LDS (coalesced payload read) ----
__global__ __launch_bounds__(TPB) void accum_kernel(
    const float2* __restrict__ pos, const float2* __restrict__ vel,
    int S, const unsigned* __restrict__ rec, const int* __restrict__ meta,
    float* __restrict__ part)
{
    __shared__ float sm[5 * NPR];   // 160 KiB: {m2,m3,m0,m1,cnt}
    const int r  = blockIdx.x, si = blockIdx.y;
    const int base = meta[r];
    const int tot  = meta[MAXR + r];
    const int lo = base + (int)((long long)tot * si / S);
    const int hi = base + (int)((long long)tot * (si + 1) / S);
    const int nbase = r << LOG2NPR;

    for (int i = threadIdx.x; i < 5 * NPR; i += TPB) sm[i] = 0.0f;
    __syncthreads();

    for (int i = lo + (int)threadIdx.x; i < hi; i += TPB) {
        unsigned p = rec[i];
        int s     = (int)(p & 0x1FFFFu);
        int local = (int)(p >> 17);
        float2 ps = pos[s], pd = pos[nbase + local];
        float x0 = pd.x - ps.x;
        float x1 = pd.y - ps.y;
        bool zmask = false;
        if (x0 == 0.0f && x1 == 0.0f) {          // rare: lazy vel check
            float2 vs = vel[s], vd = vel[nbase + local];
            zmask = (vd.x == vs.x) && (vd.y == vs.y);
        }
        atomicAdd(&sm[4 * NPR + local], 1.0f);   // count ALL edges
        if (!zmask) {
            float m0, m1, m2, m3;
            compute_msgs(x0, x1, m0, m1, m2, m3);
            atomicAdd(&sm[0 * NPR + local], m2);
            atomicAdd(&sm[1 * NPR + local], m3);
            atomicAdd(&sm[2 * NPR + local], m0);
            atomicAdd(&sm[3 * NPR + local], m1);
        }
    }
    __syncthreads();
    float* dst = part + (size_t)(r * S + si) * (5 * NPR);
    for (int i = threadIdx.x; i < 5 * NPR; i += TPB) dst[i] = sm[i];
}

// ---- phase 3: fold S partials + update net ----
__global__ __launch_bounds__(256) void reduce_node_kernel(
    const float* __restrict__ part, float2* __restrict__ out, int n, int S)
{
    int i = blockIdx.x * blockDim.x + threadIdx.x;
    if (i >= n) return;
    int r  = i >> LOG2NPR;
    int li = i & (NPR - 1);
    float a0 = 0.f, a1 = 0.f, a2 = 0.f, a3 = 0.f, c = 0.f;
    const float* p = part + (size_t)(r * S) * (5 * NPR) + li;
    for (int s = 0; s < S; ++s, p += 5 * NPR) {
        a0 += p[0 * NPR];
        a1 += p[1 * NPR];
        a2 += p[2 * NPR];
        a3 += p[3 * NPR];
        c  += p[4 * NPR];
    }
    float cm = fmaxf(c, 1.0f);
    float p0, p1;
    update_net(a0, a1, a2 / cm, a3 / cm, p0, p1);
    out[i] = make_float2(p0, p1);
}

// ---- fallback path: global atomics (proven R2) ----
__global__ __launch_bounds__(256) void zero_ws_kernel(float* __restrict__ p, int n) {
    int i = blockIdx.x * blockDim.x + threadIdx.x;
    if (i < n) p[i] = 0.0f;
}

__global__ __launch_bounds__(256) void edge_atomic_kernel(
    const float2* __restrict__ pos, const float2* __restrict__ vel,
    const int* __restrict__ ei,
    float* __restrict__ a0, float* __restrict__ a1,
    float* __restrict__ a2, float* __restrict__ a3,
    float* __restrict__ cnt, int ne)
{
    int stride = gridDim.x * blockDim.x;
    for (int e = blockIdx.x * blockDim.x + threadIdx.x; e < ne; e += stride) {
        int s = ei[e];
        int d = ei[ne + e];
        float2 ps = pos[s], pd = pos[d];
        float x0 = pd.x - ps.x, x1 = pd.y - ps.y;
        bool zmask = false;
        if (x0 == 0.0f && x1 == 0.0f) {
            float2 vs = vel[s], vd = vel[d];
            zmask = (vd.x == vs.x) && (vd.y == vs.y);
        }
        unsafeAtomicAdd(&cnt[d], 1.0f);
        if (!zmask) {
            float m0, m1, m2, m3;
            compute_msgs(x0, x1, m0, m1, m2, m3);
            unsafeAtomicAdd(&a0[d], m2);
            unsafeAtomicAdd(&a1[d], m3);
            unsafeAtomicAdd(&a2[d], m0);
            unsafeAtomicAdd(&a3[d], m1);
        }
    }
}

__global__ __launch_bounds__(256) void node_kernel(
    const float* __restrict__ a0, const float* __restrict__ a1,
    const float* __restrict__ a2, const float* __restrict__ a3,
    const float* __restrict__ cnt, float2* __restrict__ out, int n)
{
    int i = blockIdx.x * blockDim.x + threadIdx.x;
    if (i >= n) return;
    float c = fmaxf(cnt[i], 1.0f);
    float p0, p1;
    update_net(a0[i], a1[i], a2[i] / c, a3[i] / c, p0, p1);
    out[i] = make_float2(p0, p1);
}

extern "C" void kernel_launch(void* const* d_in, const int* in_sizes, int n_in,
                              void* d_out, int out_size, void* d_ws, size_t ws_size,
                              hipStream_t stream) {
    const float2* pos = (const float2*)d_in[0];
    const float2* vel = (const float2*)d_in[1];
    const int* ei = (const int*)d_in[2];
    int n  = in_sizes[0] / 2;   // 100000
    int ne = in_sizes[2] / 2;   // 6400000

    int nranges = (n + NPR - 1) / NPR;
    size_t fixed    = ((size_t)NB * MAXR * 2 + 2 * MAXR + (size_t)ne) * sizeof(int);
    size_t per_part = (size_t)nranges * 5 * NPR * sizeof(float);   // ~2.13 MB

    int S = 0;
    if (nranges <= MAXR && n <= (1 << 17) && ws_size > fixed)
        S = (int)((ws_size - fixed) / per_part);
    if (S > 19) S = 19;                 // 13*19 = 247 blocks <= 256 CUs

    if (S >= 1) {
        int* cnts = (int*)d_ws;          // [NB][MAXR]
        int* offs = cnts + NB * MAXR;    // [NB][MAXR]
        int* meta = offs + NB * MAXR;    // base[MAXR], total[MAXR]
        unsigned* rec = (unsigned*)(meta + 2 * MAXR);   // [ne] payloads
        float* part = (float*)(rec + ne);
        const int* srcs = ei;
        const int* dsts = ei + ne;

        count_kernel<<<NB, TPB, 0, stream>>>(dsts, ne, cnts);
        scan_kernel<<<1, TPB, 0, stream>>>(cnts, offs, meta, nranges);
        fill_kernel<<<NB, TPB, 0, stream>>>(srcs, dsts, ne, nranges, offs, rec);
        dim3 g(nranges, S);
        accum_kernel<<<g, TPB, 0, stream>>>(pos, vel, S, rec, meta, part);
        reduce_node_kernel<<<(n + 255) / 256, 256, 0, stream>>>(part,
                                                 (float2*)d_out, n, S);
    } else {
        float* ws = (float*)d_ws;
        float* a0  = ws;
        float* a1  = ws + n;
        float* a2  = ws + 2 * (size_t)n;
        float* a3  = ws + 3 * (size_t)n;
        float* cnt = ws + 4 * (size_t)n;
        int zeroN = 5 * n;
        zero_ws_kernel<<<(zeroN + 255) / 256, 256, 0, stream>>>(ws, zeroN);
        edge_atomic_kernel<<<(ne + 255) / 256, 256, 0, stream>>>(pos, vel, ei,
                                                a0, a1, a2, a3, cnt, ne);
        node_kernel<<<(n + 255) / 256, 256, 0, stream>>>(a0, a1, a2, a3, cnt,
                                                (float2*)d_out, n);
    }
}

// Round 6
// 281.888 us; speedup vs baseline: 5.4753x; 1.0061x over previous
//
#include <hip/hip_runtime.h>

// BiasedInterpretedFlockingModel — binned, payload-carrying, half-bucket accum.
// pos (N,2) f32, vel (N,2) f32, edge_index (2,NE) int32 -> out (N,2) f32
//
// R5: accum at 190us, HBM 3.7%, VALU 4.4%, occ 41% (1 block/CU, 160KB LDS).
// Ambiguous: LDS-atomic serialization vs latency chain. This round: 4096-node
// half-buckets (80KB LDS -> 2 blocks/CU = 32 waves) + software-pipelined
// rec/pos prefetch. If flat, atomic unit is the floor -> sort path next.

#define NPR     8192        // fill-bucket granularity (13 ranges)
#define LOG2NPR 13
#define HNPR    4096        // accum half-bucket granularity
#define MAXR    13
#define NB      256
#define TPB     1024

__device__ __forceinline__ void compute_msgs(float x0, float x1,
                                             float& m0, float& m1,
                                             float& m2, float& m3) {
    float t0 = x0 * 0.07104663f;
    m0 = (x0 - x1 / (t0 * t0 + 1.536996f)) * -0.028956918f;
    float t1 = x0 * -0.021992652f;
    m1 = (x0 - x1 * (0.8290067f - t1 * t1)) * 0.025425926f;
    float t2 = x0 * -0.083299406f;
    m2 = (x0 - t2 * t2) * -0.024002103f - 0.22298379f;
    m3 = (x1 + 2.6200492f + x0 * -0.16023761f) * 0.025031794f;
}

__device__ __forceinline__ void update_net(float y0, float y1, float y2, float y3,
                                           float& p0, float& p1) {
    float t  = y2 * 0.15994334f;
    float u0 = (y0 - (y3 + t * t) / 1.7044706f - y2) * 0.16596459f;
    float s  = y2 * -0.089175865f;
    float u1 = (y1 - s * s * y3 - y2 + y3) * -0.05459863f;
    float u2 = (y3 + y0) * 0.05392959f;
    float u3 = y2 * (12.305774f / (y2 * y2 + 63.129406f));
    p0 = ((u0 / 0.5268826f + u3 - u2) * -0.18549965f - (u1 + u2)) / 0.7328953f;
    p1 = u0 * -0.8037861f - u1 + (u3 * 1.2175907f + u2);
}

// ---- phase 0: per-(block,range) histogram of dst ----
__global__ __launch_bounds__(TPB) void count_kernel(
    const int* __restrict__ dsts, int ne, int* __restrict__ cnts /*[NB][MAXR]*/)
{
    __shared__ int h[MAXR];
    if (threadIdx.x < MAXR) h[threadIdx.x] = 0;
    __syncthreads();
    const int b  = blockIdx.x;
    const int lo = (int)(((long long)ne * b / NB) & ~3LL);
    const int hi = (b == NB - 1) ? ne : (int)(((long long)ne * (b + 1) / NB) & ~3LL);
    const int hi4 = hi & ~3;

    int c[MAXR];
#pragma unroll
    for (int rr = 0; rr < MAXR; ++rr) c[rr] = 0;

    const int4* d4 = (const int4*)dsts;
    for (int i = lo / 4 + (int)threadIdx.x; 4 * i + 3 < hi; i += TPB) {
        int4 v = d4[i];
        int r0 = v.x >> LOG2NPR, r1 = v.y >> LOG2NPR;
        int r2 = v.z >> LOG2NPR, r3 = v.w >> LOG2NPR;
#pragma unroll
        for (int rr = 0; rr < MAXR; ++rr)
            c[rr] += (r0 == rr) + (r1 == rr) + (r2 == rr) + (r3 == rr);
    }
    for (int e = hi4 + (int)threadIdx.x; e < hi; e += TPB) {
        int r = dsts[e] >> LOG2NPR;
#pragma unroll
        for (int rr = 0; rr < MAXR; ++rr) c[rr] += (r == rr);
    }
#pragma unroll
    for (int rr = 0; rr < MAXR; ++rr) {
#pragma unroll
        for (int off = 32; off; off >>= 1) c[rr] += __shfl_down(c[rr], off, 64);
    }
    if ((threadIdx.x & 63) == 0) {
#pragma unroll
        for (int rr = 0; rr < MAXR; ++rr) if (c[rr]) atomicAdd(&h[rr], c[rr]);
    }
    __syncthreads();
    if (threadIdx.x < MAXR) cnts[b * MAXR + (int)threadIdx.x] = h[threadIdx.x];
}

// ---- phase 0.5: exclusive prefix -> per-(block,range) write offsets ----
__global__ __launch_bounds__(TPB) void scan_kernel(
    const int* __restrict__ cnts, int* __restrict__ offs,
    int* __restrict__ meta /* [0,MAXR)=base, [MAXR,2*MAXR)=total */, int nranges)
{
    __shared__ int sh[NB * MAXR];
    __shared__ int tot[MAXR], bas[MAXR];
    for (int i = threadIdx.x; i < NB * MAXR; i += TPB) sh[i] = cnts[i];
    __syncthreads();
    if (threadIdx.x < (unsigned)nranges) {
        int r = threadIdx.x, run = 0;
        for (int b = 0; b < NB; ++b) {
            int v = sh[b * MAXR + r];
            sh[b * MAXR + r] = run;
            run += v;
        }
        tot[r] = run;
    }
    __syncthreads();
    if (threadIdx.x == 0) {
        int acc = 0;
        for (int r = 0; r < nranges; ++r) { bas[r] = acc; acc += tot[r]; }
    }
    __syncthreads();
    for (int i = threadIdx.x; i < NB * MAXR; i += TPB) {
        int r = i % MAXR;
        if (r < nranges) offs[i] = sh[i] + bas[r];
    }
    if (threadIdx.x < (unsigned)nranges) {
        meta[threadIdx.x] = bas[threadIdx.x];
        meta[MAXR + threadIdx.x] = tot[threadIdx.x];
    }
}

// ---- phase 1: write packed (local<<17|src) into range buckets ----
__global__ __launch_bounds__(TPB) void fill_kernel(
    const int* __restrict__ srcs, const int* __restrict__ dsts, int ne, int nranges,
    const int* __restrict__ offs, unsigned* __restrict__ rec)
{
    __shared__ int cur[MAXR];
    const int b = blockIdx.x;
    if (threadIdx.x < (unsigned)nranges)
        cur[threadIdx.x] = offs[b * MAXR + (int)threadIdx.x];
    __syncthreads();
    const int lo = (int)(((long long)ne * b / NB) & ~3LL);
    const int hi = (b == NB - 1) ? ne : (int)(((long long)ne * (b + 1) / NB) & ~3LL);
    const int hi4 = hi & ~3;
    const int lane = (int)(threadIdx.x & 63);

    const int4* d4 = (const int4*)dsts;
    const int4* s4 = (const int4*)srcs;
    for (int i = lo / 4 + (int)threadIdx.x; 4 * i + 3 < hi; i += TPB) {
        int4 vd = d4[i];
        int4 vs = s4[i];
#pragma unroll
        for (int j = 0; j < 4; ++j) {
            int d = (j == 0) ? vd.x : (j == 1) ? vd.y : (j == 2) ? vd.z : vd.w;
            int s = (j == 0) ? vs.x : (j == 1) ? vs.y : (j == 2) ? vs.z : vs.w;
            int r = d >> LOG2NPR;
            unsigned p = ((unsigned)(d & (NPR - 1)) << 17) | (unsigned)s;
            for (int rr = 0; rr < nranges; ++rr) {
                unsigned long long m = __ballot(r == rr);
                if (!m) continue;
                int leader = (int)__builtin_ctzll(m);
                int base = 0;
                if (lane == leader) base = atomicAdd(&cur[rr], (int)__popcll(m));
                base = __shfl(base, leader, 64);
                if (r == rr) {
                    int rank = (int)__popcll(m & ((1ull << lane) - 1ull));
                    rec[base + rank] = p;
                }
            }
        }
    }
    for (int e = hi4 + (int)threadIdx.x; e < hi; e += TPB) {   // tail
        int d = dsts[e];
        int s = srcs[e];
        int r = d >> LOG2NPR;
        unsigned p = ((unsigned)(d & (NPR - 1)) << 17) | (unsigned)s;
        for (int rr = 0; rr < nranges; ++rr) {
            unsigned long long m = __ballot(r == rr);
            if (!m) continue;
            int leader = (int)__builtin_ctzll(m);
            int base = 0;
            if (lane == leader) base = atomicAdd(&cur[rr], (int)__popcll(m));
            base = __shfl(base, leader, 64);
            if (r == rr) {
                int rank = (int)__popcll(m & ((1ull << lane) - 1ull));
                rec[base + rank] = p;
            }
        }
    }
}

// ---- phase 2: half-bucket LDS accumulation, software-pipelined ----
// grid (nranges, S, 2); block owns 4096 nodes (80KB LDS -> 2 blocks/CU).
__global__ __launch_bounds__(TPB, 8) void accum_kernel(
    const float2* __restrict__ pos, const float2* __restrict__ vel,
    int S, const unsigned* __restrict__ rec, const int* __restrict__ meta,
    float* __restrict__ part)
{
    __shared__ float sm[5 * HNPR];   // 80 KiB: {m2,m3,m0,m1,cnt}
    const int r  = blockIdx.x, si = blockIdx.y, h = blockIdx.z;
    const int base = meta[r];
    const int tot  = meta[MAXR + r];
    const int lo = base + (int)((long long)tot * si / S);
    const int hi = base + (int)((long long)tot * (si + 1) / S);
    const int rbase = r << LOG2NPR;  // global node base of full range
    const int hb    = h << 12;       // half offset within range

    for (int i = threadIdx.x; i < 5 * HNPR; i += TPB) sm[i] = 0.0f;
    __syncthreads();

    // software pipeline: fetch (rec + pos gathers) one iteration ahead
    auto fetch = [&](int idx, bool& val, int& lh_o, int& s_o,
                     float2& ps_o, float2& pd_o) {
        val = false;
        if (idx < hi) {
            unsigned p = rec[idx];
            int local = (int)(p >> 17);
            int lh = local - hb;
            if ((unsigned)lh < (unsigned)HNPR) {
                val = true;
                lh_o = lh;
                s_o  = (int)(p & 0x1FFFFu);
                ps_o = pos[s_o];
                pd_o = pos[rbase + local];
            }
        }
    };

    int i = lo + (int)threadIdx.x;
    bool v; int lh, s; float2 ps, pd;
    fetch(i, v, lh, s, ps, pd);

    for (; i < hi; i += TPB) {
        bool vn; int lhn, sn; float2 psn, pdn;
        fetch(i + TPB, vn, lhn, sn, psn, pdn);

        if (v) {
            float x0 = pd.x - ps.x;
            float x1 = pd.y - ps.y;
            bool zmask = false;
            if (x0 == 0.0f && x1 == 0.0f) {      // rare: lazy vel check
                float2 vs = vel[s], vd = vel[rbase + hb + lh];
                zmask = (vd.x == vs.x) && (vd.y == vs.y);
            }
            atomicAdd(&sm[4 * HNPR + lh], 1.0f); // count ALL edges
            if (!zmask) {
                float m0, m1, m2, m3;
                compute_msgs(x0, x1, m0, m1, m2, m3);
                atomicAdd(&sm[0 * HNPR + lh], m2);
                atomicAdd(&sm[1 * HNPR + lh], m3);
                atomicAdd(&sm[2 * HNPR + lh], m0);
                atomicAdd(&sm[3 * HNPR + lh], m1);
            }
        }
        v = vn; lh = lhn; s = sn; ps = psn; pd = pdn;
    }
    __syncthreads();
    float* dst = part + (size_t)((r * 2 + h) * S + si) * (5 * HNPR);
    for (int i2 = threadIdx.x; i2 < 5 * HNPR; i2 += TPB) dst[i2] = sm[i2];
}

// ---- phase 3: fold S partials + update net ----
__global__ __launch_bounds__(256) void reduce_node_kernel(
    const float* __restrict__ part, float2* __restrict__ out, int n, int S)
{
    int i = blockIdx.x * blockDim.x + threadIdx.x;
    if (i >= n) return;
    int r  = i >> LOG2NPR;
    int h  = (i >> 12) & 1;
    int li = i & (HNPR - 1);
    float a0 = 0.f, a1 = 0.f, a2 = 0.f, a3 = 0.f, c = 0.f;
    const float* p = part + (size_t)((r * 2 + h) * S) * (5 * HNPR) + li;
    for (int s = 0; s < S; ++s, p += 5 * HNPR) {
        a0 += p[0 * HNPR];
        a1 += p[1 * HNPR];
        a2 += p[2 * HNPR];
        a3 += p[3 * HNPR];
        c  += p[4 * HNPR];
    }
    float cm = fmaxf(c, 1.0f);
    float p0, p1;
    update_net(a0, a1, a2 / cm, a3 / cm, p0, p1);
    out[i] = make_float2(p0, p1);
}

// ---- fallback path: global atomics (proven R2) ----
__global__ __launch_bounds__(256) void zero_ws_kernel(float* __restrict__ p, int n) {
    int i = blockIdx.x * blockDim.x + threadIdx.x;
    if (i < n) p[i] = 0.0f;
}

__global__ __launch_bounds__(256) void edge_atomic_kernel(
    const float2* __restrict__ pos, const float2* __restrict__ vel,
    const int* __restrict__ ei,
    float* __restrict__ a0, float* __restrict__ a1,
    float* __restrict__ a2, float* __restrict__ a3,
    float* __restrict__ cnt, int ne)
{
    int stride = gridDim.x * blockDim.x;
    for (int e = blockIdx.x * blockDim.x + threadIdx.x; e < ne; e += stride) {
        int s = ei[e];
        int d = ei[ne + e];
        float2 ps = pos[s], pd = pos[d];
        float x0 = pd.x - ps.x, x1 = pd.y - ps.y;
        bool zmask = false;
        if (x0 == 0.0f && x1 == 0.0f) {
            float2 vs = vel[s], vd = vel[d];
            zmask = (vd.x == vs.x) && (vd.y == vs.y);
        }
        unsafeAtomicAdd(&cnt[d], 1.0f);
        if (!zmask) {
            float m0, m1, m2, m3;
            compute_msgs(x0, x1, m0, m1, m2, m3);
            unsafeAtomicAdd(&a0[d], m2);
            unsafeAtomicAdd(&a1[d], m3);
            unsafeAtomicAdd(&a2[d], m0);
            unsafeAtomicAdd(&a3[d], m1);
        }
    }
}

__global__ __launch_bounds__(256) void node_kernel(
    const float* __restrict__ a0, const float* __restrict__ a1,
    const float* __restrict__ a2, const float* __restrict__ a3,
    const float* __restrict__ cnt, float2* __restrict__ out, int n)
{
    int i = blockIdx.x * blockDim.x + threadIdx.x;
    if (i >= n) return;
    float c = fmaxf(cnt[i], 1.0f);
    float p0, p1;
    update_net(a0[i], a1[i], a2[i] / c, a3[i] / c, p0, p1);
    out[i] = make_float2(p0, p1);
}

extern "C" void kernel_launch(void* const* d_in, const int* in_sizes, int n_in,
                              void* d_out, int out_size, void* d_ws, size_t ws_size,
                              hipStream_t stream) {
    const float2* pos = (const float2*)d_in[0];
    const float2* vel = (const float2*)d_in[1];
    const int* ei = (const int*)d_in[2];
    int n  = in_sizes[0] / 2;   // 100000
    int ne = in_sizes[2] / 2;   // 6400000

    int nranges = (n + NPR - 1) / NPR;
    size_t fixed    = ((size_t)NB * MAXR * 2 + 2 * MAXR + (size_t)ne) * sizeof(int);
    size_t per_part = (size_t)nranges * 2 * 5 * HNPR * sizeof(float); // == R5 size

    int S = 0;
    if (nranges <= MAXR && n <= (1 << 17) && ws_size > fixed)
        S = (int)((ws_size - fixed) / per_part);
    if (S > 19) S = 19;

    if (S >= 1) {
        int* cnts = (int*)d_ws;          // [NB][MAXR]
        int* offs = cnts + NB * MAXR;    // [NB][MAXR]
        int* meta = offs + NB * MAXR;    // base[MAXR], total[MAXR]
        unsigned* rec = (unsigned*)(meta + 2 * MAXR);   // [ne] payloads
        float* part = (float*)(rec + ne);
        const int* srcs = ei;
        const int* dsts = ei + ne;

        count_kernel<<<NB, TPB, 0, stream>>>(dsts, ne, cnts);
        scan_kernel<<<1, TPB, 0, stream>>>(cnts, offs, meta, nranges);
        fill_kernel<<<NB, TPB, 0, stream>>>(srcs, dsts, ne, nranges, offs, rec);
        dim3 g(nranges, S, 2);
        accum_kernel<<<g, TPB, 0, stream>>>(pos, vel, S, rec, meta, part);
        reduce_node_kernel<<<(n + 255) / 256, 256, 0, stream>>>(part,
                                                 (float2*)d_out, n, S);
    } else {
        float* ws = (float*)d_ws;
        float* a0  = ws;
        float* a1  = ws + n;
        float* a2  = ws + 2 * (size_t)n;
        float* a3  = ws + 3 * (size_t)n;
        float* cnt = ws + 4 * (size_t)n;
        int zeroN = 5 * n;
        zero_ws_kernel<<<(zeroN + 255) / 256, 256, 0, stream>>>(ws, zeroN);
        edge_atomic_kernel<<<(ne + 255) / 256, 256, 0, stream>>>(pos, vel, ei,
                                                a0, a1, a2, a3, cnt, ne);
        node_kernel<<<(n + 255) / 256, 256, 0, stream>>>(a0, a1, a2, a3, cnt,
                                                (float2*)d_out, n);
    }
}

// Round 7
// 155.207 us; speedup vs baseline: 9.9442x; 1.8162x over previous
//
#include <hip/hip_runtime.h>

// BiasedInterpretedFlockingModel — binned + packed-u64 LDS atomics.
// pos (N,2) f32, vel (N,2) f32, edge_index (2,NE) int32 -> out (N,2) f32
//
// R5/R6 proved accum is LDS-atomic-lane-op bound (~3.5 cyc/lane-op/CU;
// 190us invariant under 2x occupancy and 2x scan work). This round packs the
// 5 f32 atomics/edge into 2 u64 atomics/edge, fixed-point with bias:
//   F1 += (1<<46) | (round(m2*8192)+8192)<<23 | (round(m3*8192)+8192)
//   F2 +=          (round(m0*8192)+8192)<<23 | (round(m1*8192)+8192)
// |m| < 0.6 (bounded by coefficients, |x|<=12) -> per-edge field <= 13107;
// 23-bit fields hold >=640 edges/node (realistic max in-degree ~130).
// Quantization (rint) <= 6e-5/edge. cnt rides in F1[46:64).

#define NPR     8192
#define LOG2NPR 13
#define MAXR    13
#define NB      256
#define TPB     1024

#define MSCALE  8192.0f
#define MBIAS   8192
#define FMASK   0x7FFFFFULL

__device__ __forceinline__ void compute_msgs(float x0, float x1,
                                             float& m0, float& m1,
                                             float& m2, float& m3) {
    float t0 = x0 * 0.07104663f;
    m0 = (x0 - x1 / (t0 * t0 + 1.536996f)) * -0.028956918f;
    float t1 = x0 * -0.021992652f;
    m1 = (x0 - x1 * (0.8290067f - t1 * t1)) * 0.025425926f;
    float t2 = x0 * -0.083299406f;
    m2 = (x0 - t2 * t2) * -0.024002103f - 0.22298379f;
    m3 = (x1 + 2.6200492f + x0 * -0.16023761f) * 0.025031794f;
}

__device__ __forceinline__ void update_net(float y0, float y1, float y2, float y3,
                                           float& p0, float& p1) {
    float t  = y2 * 0.15994334f;
    float u0 = (y0 - (y3 + t * t) / 1.7044706f - y2) * 0.16596459f;
    float s  = y2 * -0.089175865f;
    float u1 = (y1 - s * s * y3 - y2 + y3) * -0.05459863f;
    float u2 = (y3 + y0) * 0.05392959f;
    float u3 = y2 * (12.305774f / (y2 * y2 + 63.129406f));
    p0 = ((u0 / 0.5268826f + u3 - u2) * -0.18549965f - (u1 + u2)) / 0.7328953f;
    p1 = u0 * -0.8037861f - u1 + (u3 * 1.2175907f + u2);
}

// ---- phase 0: per-(block,range) histogram of dst ----
__global__ __launch_bounds__(TPB) void count_kernel(
    const int* __restrict__ dsts, int ne, int* __restrict__ cnts /*[NB][MAXR]*/)
{
    __shared__ int h[MAXR];
    if (threadIdx.x < MAXR) h[threadIdx.x] = 0;
    __syncthreads();
    const int b  = blockIdx.x;
    const int lo = (int)(((long long)ne * b / NB) & ~3LL);
    const int hi = (b == NB - 1) ? ne : (int)(((long long)ne * (b + 1) / NB) & ~3LL);
    const int hi4 = hi & ~3;

    int c[MAXR];
#pragma unroll
    for (int rr = 0; rr < MAXR; ++rr) c[rr] = 0;

    const int4* d4 = (const int4*)dsts;
    for (int i = lo / 4 + (int)threadIdx.x; 4 * i + 3 < hi; i += TPB) {
        int4 v = d4[i];
        int r0 = v.x >> LOG2NPR, r1 = v.y >> LOG2NPR;
        int r2 = v.z >> LOG2NPR, r3 = v.w >> LOG2NPR;
#pragma unroll
        for (int rr = 0; rr < MAXR; ++rr)
            c[rr] += (r0 == rr) + (r1 == rr) + (r2 == rr) + (r3 == rr);
    }
    for (int e = hi4 + (int)threadIdx.x; e < hi; e += TPB) {
        int r = dsts[e] >> LOG2NPR;
#pragma unroll
        for (int rr = 0; rr < MAXR; ++rr) c[rr] += (r == rr);
    }
#pragma unroll
    for (int rr = 0; rr < MAXR; ++rr) {
#pragma unroll
        for (int off = 32; off; off >>= 1) c[rr] += __shfl_down(c[rr], off, 64);
    }
    if ((threadIdx.x & 63) == 0) {
#pragma unroll
        for (int rr = 0; rr < MAXR; ++rr) if (c[rr]) atomicAdd(&h[rr], c[rr]);
    }
    __syncthreads();
    if (threadIdx.x < MAXR) cnts[b * MAXR + (int)threadIdx.x] = h[threadIdx.x];
}

// ---- phase 0.5: exclusive prefix -> per-(block,range) write offsets ----
__global__ __launch_bounds__(TPB) void scan_kernel(
    const int* __restrict__ cnts, int* __restrict__ offs,
    int* __restrict__ meta /* [0,MAXR)=base, [MAXR,2*MAXR)=total */, int nranges)
{
    __shared__ int sh[NB * MAXR];
    __shared__ int tot[MAXR], bas[MAXR];
    for (int i = threadIdx.x; i < NB * MAXR; i += TPB) sh[i] = cnts[i];
    __syncthreads();
    if (threadIdx.x < (unsigned)nranges) {
        int r = threadIdx.x, run = 0;
        for (int b = 0; b < NB; ++b) {
            int v = sh[b * MAXR + r];
            sh[b * MAXR + r] = run;
            run += v;
        }
        tot[r] = run;
    }
    __syncthreads();
    if (threadIdx.x == 0) {
        int acc = 0;
        for (int r = 0; r < nranges; ++r) { bas[r] = acc; acc += tot[r]; }
    }
    __syncthreads();
    for (int i = threadIdx.x; i < NB * MAXR; i += TPB) {
        int r = i % MAXR;
        if (r < nranges) offs[i] = sh[i] + bas[r];
    }
    if (threadIdx.x < (unsigned)nranges) {
        meta[threadIdx.x] = bas[threadIdx.x];
        meta[MAXR + threadIdx.x] = tot[threadIdx.x];
    }
}

// ---- phase 1: write packed (local<<17|src) into range buckets ----
__global__ __launch_bounds__(TPB) void fill_kernel(
    const int* __restrict__ srcs, const int* __restrict__ dsts, int ne, int nranges,
    const int* __restrict__ offs, unsigned* __restrict__ rec)
{
    __shared__ int cur[MAXR];
    const int b = blockIdx.x;
    if (threadIdx.x < (unsigned)nranges)
        cur[threadIdx.x] = offs[b * MAXR + (int)threadIdx.x];
    __syncthreads();
    const int lo = (int)(((long long)ne * b / NB) & ~3LL);
    const int hi = (b == NB - 1) ? ne : (int)(((long long)ne * (b + 1) / NB) & ~3LL);
    const int hi4 = hi & ~3;
    const int lane = (int)(threadIdx.x & 63);

    const int4* d4 = (const int4*)dsts;
    const int4* s4 = (const int4*)srcs;
    for (int i = lo / 4 + (int)threadIdx.x; 4 * i + 3 < hi; i += TPB) {
        int4 vd = d4[i];
        int4 vs = s4[i];
#pragma unroll
        for (int j = 0; j < 4; ++j) {
            int d = (j == 0) ? vd.x : (j == 1) ? vd.y : (j == 2) ? vd.z : vd.w;
            int s = (j == 0) ? vs.x : (j == 1) ? vs.y : (j == 2) ? vs.z : vs.w;
            int r = d >> LOG2NPR;
            unsigned p = ((unsigned)(d & (NPR - 1)) << 17) | (unsigned)s;
            for (int rr = 0; rr < nranges; ++rr) {
                unsigned long long m = __ballot(r == rr);
                if (!m) continue;
                int leader = (int)__builtin_ctzll(m);
                int base = 0;
                if (lane == leader) base = atomicAdd(&cur[rr], (int)__popcll(m));
                base = __shfl(base, leader, 64);
                if (r == rr) {
                    int rank = (int)__popcll(m & ((1ull << lane) - 1ull));
                    rec[base + rank] = p;
                }
            }
        }
    }
    for (int e = hi4 + (int)threadIdx.x; e < hi; e += TPB) {   // tail
        int d = dsts[e];
        int s = srcs[e];
        int r = d >> LOG2NPR;
        unsigned p = ((unsigned)(d & (NPR - 1)) << 17) | (unsigned)s;
        for (int rr = 0; rr < nranges; ++rr) {
            unsigned long long m = __ballot(r == rr);
            if (!m) continue;
            int leader = (int)__builtin_ctzll(m);
            int base = 0;
            if (lane == leader) base = atomicAdd(&cur[rr], (int)__popcll(m));
            base = __shfl(base, leader, 64);
            if (r == rr) {
                int rank = (int)__popcll(m & ((1ull << lane) - 1ull));
                rec[base + rank] = p;
            }
        }
    }
}

// ---- phase 2: bucket accumulation, 2 packed u64 LDS atomics per edge ----
__global__ __launch_bounds__(TPB) void accum_kernel(
    const float2* __restrict__ pos, const float2* __restrict__ vel,
    int S, const unsigned* __restrict__ rec, const int* __restrict__ meta,
    unsigned long long* __restrict__ part)
{
    __shared__ unsigned long long sm[2 * NPR];   // 128 KiB: F1 plane, F2 plane
    const int r  = blockIdx.x, si = blockIdx.y;
    const int base = meta[r];
    const int tot  = meta[MAXR + r];
    const int lo = base + (int)((long long)tot * si / S);
    const int hi = base + (int)((long long)tot * (si + 1) / S);
    const int nbase = r << LOG2NPR;

    for (int i = threadIdx.x; i < 2 * NPR; i += TPB) sm[i] = 0ull;
    __syncthreads();

    // 1-ahead prefetch of rec + pos gathers
    int i = lo + (int)threadIdx.x;
    unsigned p = 0; float2 ps = {}, pd = {};
    if (i < hi) {
        p = rec[i];
        ps = pos[p & 0x1FFFFu];
        pd = pos[nbase + (int)(p >> 17)];
    }

    for (; i < hi; i += TPB) {
        unsigned pn = 0; float2 psn = {}, pdn = {};
        if (i + TPB < hi) {
            pn = rec[i + TPB];
            psn = pos[pn & 0x1FFFFu];
            pdn = pos[nbase + (int)(pn >> 17)];
        }

        int local = (int)(p >> 17);
        float x0 = pd.x - ps.x;
        float x1 = pd.y - ps.y;

        float m0 = 0.f, m1 = 0.f, m2 = 0.f, m3 = 0.f;
        bool zmask = false;
        if (x0 == 0.0f && x1 == 0.0f) {          // rare: lazy vel check
            int s = (int)(p & 0x1FFFFu);
            float2 vs = vel[s], vd = vel[nbase + local];
            zmask = (vd.x == vs.x) && (vd.y == vs.y);
        }
        if (!zmask) compute_msgs(x0, x1, m0, m1, m2, m3);

        unsigned v0 = (unsigned)((int)rintf(m0 * MSCALE) + MBIAS);
        unsigned v1 = (unsigned)((int)rintf(m1 * MSCALE) + MBIAS);
        unsigned v2 = (unsigned)((int)rintf(m2 * MSCALE) + MBIAS);
        unsigned v3 = (unsigned)((int)rintf(m3 * MSCALE) + MBIAS);
        unsigned long long F1 = (1ULL << 46) |
                                ((unsigned long long)v2 << 23) | v3;
        unsigned long long F2 = ((unsigned long long)v0 << 23) | v1;
        atomicAdd(&sm[local], F1);
        atomicAdd(&sm[NPR + local], F2);

        p = pn; ps = psn; pd = pdn;
    }
    __syncthreads();
    unsigned long long* dst = part + (size_t)(r * S + si) * (2 * NPR);
    for (int k = threadIdx.x; k < 2 * NPR; k += TPB) dst[k] = sm[k];
}

// ---- phase 3: fold S partials, decode fixed-point, update net ----
__global__ __launch_bounds__(256) void reduce_node_kernel(
    const unsigned long long* __restrict__ part, float2* __restrict__ out,
    int n, int S)
{
    int i = blockIdx.x * blockDim.x + threadIdx.x;
    if (i >= n) return;
    int r  = i >> LOG2NPR;
    int li = i & (NPR - 1);
    unsigned long long F1 = 0ull, F2 = 0ull;
    const unsigned long long* p = part + (size_t)(r * S) * (2 * NPR) + li;
    for (int s = 0; s < S; ++s, p += 2 * NPR) {
        F1 += p[0];
        F2 += p[NPR];
    }
    float c   = (float)(F1 >> 46);
    float bia = c * (float)MBIAS;
    const float inv = 1.0f / MSCALE;
    float y0 = ((float)(unsigned)((F1 >> 23) & FMASK) - bia) * inv;  // sum m2
    float y1 = ((float)(unsigned)(F1 & FMASK)         - bia) * inv;  // sum m3
    float s0 = ((float)(unsigned)((F2 >> 23) & FMASK) - bia) * inv;  // sum m0
    float s1 = ((float)(unsigned)(F2 & FMASK)         - bia) * inv;  // sum m1
    float cm = fmaxf(c, 1.0f);
    float p0, p1;
    update_net(y0, y1, s0 / cm, s1 / cm, p0, p1);
    out[i] = make_float2(p0, p1);
}

// ---- fallback path: global atomics (proven R2) ----
__global__ __launch_bounds__(256) void zero_ws_kernel(float* __restrict__ p, int n) {
    int i = blockIdx.x * blockDim.x + threadIdx.x;
    if (i < n) p[i] = 0.0f;
}

__global__ __launch_bounds__(256) void edge_atomic_kernel(
    const float2* __restrict__ pos, const float2* __restrict__ vel,
    const int* __restrict__ ei,
    float* __restrict__ a0, float* __restrict__ a1,
    float* __restrict__ a2, float* __restrict__ a3,
    float* __restrict__ cnt, int ne)
{
    int stride = gridDim.x * blockDim.x;
    for (int e = blockIdx.x * blockDim.x + threadIdx.x; e < ne; e += stride) {
        int s = ei[e];
        int d = ei[ne + e];
        float2 ps = pos[s], pd = pos[d];
        float x0 = pd.x - ps.x, x1 = pd.y - ps.y;
        bool zmask = false;
        if (x0 == 0.0f && x1 == 0.0f) {
            float2 vs = vel[s], vd = vel[d];
            zmask = (vd.x == vs.x) && (vd.y == vs.y);
        }
        unsafeAtomicAdd(&cnt[d], 1.0f);
        if (!zmask) {
            float m0, m1, m2, m3;
            compute_msgs(x0, x1, m0, m1, m2, m3);
            unsafeAtomicAdd(&a0[d], m2);
            unsafeAtomicAdd(&a1[d], m3);
            unsafeAtomicAdd(&a2[d], m0);
            unsafeAtomicAdd(&a3[d], m1);
        }
    }
}

__global__ __launch_bounds__(256) void node_kernel(
    const float* __restrict__ a0, const float* __restrict__ a1,
    const float* __restrict__ a2, const float* __restrict__ a3,
    const float* __restrict__ cnt, float2* __restrict__ out, int n)
{
    int i = blockIdx.x * blockDim.x + threadIdx.x;
    if (i >= n) return;
    float c = fmaxf(cnt[i], 1.0f);
    float p0, p1;
    update_net(a0[i], a1[i], a2[i] / c, a3[i] / c, p0, p1);
    out[i] = make_float2(p0, p1);
}

extern "C" void kernel_launch(void* const* d_in, const int* in_sizes, int n_in,
                              void* d_out, int out_size, void* d_ws, size_t ws_size,
                              hipStream_t stream) {
    const float2* pos = (const float2*)d_in[0];
    const float2* vel = (const float2*)d_in[1];
    const int* ei = (const int*)d_in[2];
    int n  = in_sizes[0] / 2;   // 100000
    int ne = in_sizes[2] / 2;   // 6400000

    int nranges = (n + NPR - 1) / NPR;
    size_t fixed    = ((size_t)NB * MAXR * 2 + 2 * MAXR + (size_t)ne) * sizeof(int);
    // align part to 8B
    fixed = (fixed + 7) & ~(size_t)7;
    size_t per_part = (size_t)nranges * 2 * NPR * sizeof(unsigned long long); // 1.66MB/slice

    int S = 0;
    if (nranges <= MAXR && n <= (1 << 17) && ws_size > fixed)
        S = (int)((ws_size - fixed) / per_part);
    if (S > 19) S = 19;                 // 13*19 = 247 blocks <= 256 CUs

    if (S >= 1) {
        int* cnts = (int*)d_ws;          // [NB][MAXR]
        int* offs = cnts + NB * MAXR;    // [NB][MAXR]
        int* meta = offs + NB * MAXR;    // base[MAXR], total[MAXR]
        unsigned* rec = (unsigned*)(meta + 2 * MAXR);   // [ne] payloads
        unsigned long long* part =
            (unsigned long long*)(((uintptr_t)d_ws + fixed + 7) & ~(uintptr_t)7);
        const int* srcs = ei;
        const int* dsts = ei + ne;

        count_kernel<<<NB, TPB, 0, stream>>>(dsts, ne, cnts);
        scan_kernel<<<1, TPB, 0, stream>>>(cnts, offs, meta, nranges);
        fill_kernel<<<NB, TPB, 0, stream>>>(srcs, dsts, ne, nranges, offs, rec);
        dim3 g(nranges, S);
        accum_kernel<<<g, TPB, 0, stream>>>(pos, vel, S, rec, meta, part);
        reduce_node_kernel<<<(n + 255) / 256, 256, 0, stream>>>(part,
                                                 (float2*)d_out, n, S);
    } else {
        float* ws = (float*)d_ws;
        float* a0  = ws;
        float* a1  = ws + n;
        float* a2  = ws + 2 * (size_t)n;
        float* a3  = ws + 3 * (size_t)n;
        float* cnt = ws + 4 * (size_t)n;
        int zeroN = 5 * n;
        zero_ws_kernel<<<(zeroN + 255) / 256, 256, 0, stream>>>(ws, zeroN);
        edge_atomic_kernel<<<(ne + 255) / 256, 256, 0, stream>>>(pos, vel, ei,
                                                a0, a1, a2, a3, cnt, ne);
        node_kernel<<<(n + 255) / 256, 256, 0, stream>>>(a0, a1, a2, a3, cnt,
                                                (float2*)d_out, n);
    }
}

// Round 8
// 106.524 us; speedup vs baseline: 14.4888x; 1.4570x over previous
//
#include <hip/hip_runtime.h>

// BiasedInterpretedFlockingModel — binned + packed-u64 LDS atomics.
// pos (N,2) f32, vel (N,2) f32, edge_index (2,NE) int32 -> out (N,2) f32
//
// R7: fill was VALU-bound (54%) on the 13-range ballot-aggregation loop.
// R5-R7 established DS atomics cost ~3.5 cyc/lane-op -> a plain LDS atomic
// slot grab (1 lane-op/edge) is cheaper than the ballot loop. accum keeps
// the 2-packed-u64-per-edge scheme (validated: 190us -> ~68us = 2/5 ratio):
//   F1 += (1<<46) | (round(m2*8192)+8192)<<23 | (round(m3*8192)+8192)
//   F2 +=          (round(m0*8192)+8192)<<23 | (round(m1*8192)+8192)

#define NPR     8192
#define LOG2NPR 13
#define MAXR    13
#define NB      512
#define TPB     1024

#define MSCALE  8192.0f
#define MBIAS   8192
#define FMASK   0x7FFFFFULL

__device__ __forceinline__ void compute_msgs(float x0, float x1,
                                             float& m0, float& m1,
                                             float& m2, float& m3) {
    float t0 = x0 * 0.07104663f;
    m0 = (x0 - x1 / (t0 * t0 + 1.536996f)) * -0.028956918f;
    float t1 = x0 * -0.021992652f;
    m1 = (x0 - x1 * (0.8290067f - t1 * t1)) * 0.025425926f;
    float t2 = x0 * -0.083299406f;
    m2 = (x0 - t2 * t2) * -0.024002103f - 0.22298379f;
    m3 = (x1 + 2.6200492f + x0 * -0.16023761f) * 0.025031794f;
}

__device__ __forceinline__ void update_net(float y0, float y1, float y2, float y3,
                                           float& p0, float& p1) {
    float t  = y2 * 0.15994334f;
    float u0 = (y0 - (y3 + t * t) / 1.7044706f - y2) * 0.16596459f;
    float s  = y2 * -0.089175865f;
    float u1 = (y1 - s * s * y3 - y2 + y3) * -0.05459863f;
    float u2 = (y3 + y0) * 0.05392959f;
    float u3 = y2 * (12.305774f / (y2 * y2 + 63.129406f));
    p0 = ((u0 / 0.5268826f + u3 - u2) * -0.18549965f - (u1 + u2)) / 0.7328953f;
    p1 = u0 * -0.8037861f - u1 + (u3 * 1.2175907f + u2);
}

// ---- phase 0: per-(block,range) histogram of dst ----
__global__ __launch_bounds__(TPB) void count_kernel(
    const int* __restrict__ dsts, int ne, int* __restrict__ cnts /*[NB][MAXR]*/)
{
    __shared__ int h[MAXR];
    if (threadIdx.x < MAXR) h[threadIdx.x] = 0;
    __syncthreads();
    const int b  = blockIdx.x;
    const int lo = (int)(((long long)ne * b / NB) & ~3LL);
    const int hi = (b == NB - 1) ? ne : (int)(((long long)ne * (b + 1) / NB) & ~3LL);
    const int hi4 = hi & ~3;

    int c[MAXR];
#pragma unroll
    for (int rr = 0; rr < MAXR; ++rr) c[rr] = 0;

    const int4* d4 = (const int4*)dsts;
    for (int i = lo / 4 + (int)threadIdx.x; 4 * i + 3 < hi; i += TPB) {
        int4 v = d4[i];
        int r0 = v.x >> LOG2NPR, r1 = v.y >> LOG2NPR;
        int r2 = v.z >> LOG2NPR, r3 = v.w >> LOG2NPR;
#pragma unroll
        for (int rr = 0; rr < MAXR; ++rr)
            c[rr] += (r0 == rr) + (r1 == rr) + (r2 == rr) + (r3 == rr);
    }
    for (int e = hi4 + (int)threadIdx.x; e < hi; e += TPB) {
        int r = dsts[e] >> LOG2NPR;
#pragma unroll
        for (int rr = 0; rr < MAXR; ++rr) c[rr] += (r == rr);
    }
#pragma unroll
    for (int rr = 0; rr < MAXR; ++rr) {
#pragma unroll
        for (int off = 32; off; off >>= 1) c[rr] += __shfl_down(c[rr], off, 64);
    }
    if ((threadIdx.x & 63) == 0) {
#pragma unroll
        for (int rr = 0; rr < MAXR; ++rr) if (c[rr]) atomicAdd(&h[rr], c[rr]);
    }
    __syncthreads();
    if (threadIdx.x < MAXR) cnts[b * MAXR + (int)threadIdx.x] = h[threadIdx.x];
}

// ---- phase 0.5: exclusive prefix -> per-(block,range) write offsets ----
__global__ __launch_bounds__(TPB) void scan_kernel(
    const int* __restrict__ cnts, int* __restrict__ offs,
    int* __restrict__ meta /* [0,MAXR)=base, [MAXR,2*MAXR)=total */, int nranges)
{
    __shared__ int sh[NB * MAXR];
    __shared__ int tot[MAXR], bas[MAXR];
    for (int i = threadIdx.x; i < NB * MAXR; i += TPB) sh[i] = cnts[i];
    __syncthreads();
    if (threadIdx.x < (unsigned)nranges) {
        int r = threadIdx.x, run = 0;
        for (int b = 0; b < NB; ++b) {
            int v = sh[b * MAXR + r];
            sh[b * MAXR + r] = run;
            run += v;
        }
        tot[r] = run;
    }
    __syncthreads();
    if (threadIdx.x == 0) {
        int acc = 0;
        for (int r = 0; r < nranges; ++r) { bas[r] = acc; acc += tot[r]; }
    }
    __syncthreads();
    for (int i = threadIdx.x; i < NB * MAXR; i += TPB) {
        int r = i % MAXR;
        if (r < nranges) offs[i] = sh[i] + bas[r];
    }
    if (threadIdx.x < (unsigned)nranges) {
        meta[threadIdx.x] = bas[threadIdx.x];
        meta[MAXR + threadIdx.x] = tot[threadIdx.x];
    }
}

// ---- phase 1: write packed (local<<17|src) into range buckets ----
// Plain LDS-atomic slot grab: 1 DS lane-op/edge (cheaper than ballot loop).
__global__ __launch_bounds__(TPB) void fill_kernel(
    const int* __restrict__ srcs, const int* __restrict__ dsts, int ne, int nranges,
    const int* __restrict__ offs, unsigned* __restrict__ rec)
{
    __shared__ int cur[MAXR];
    const int b = blockIdx.x;
    if (threadIdx.x < (unsigned)nranges)
        cur[threadIdx.x] = offs[b * MAXR + (int)threadIdx.x];
    __syncthreads();
    const int lo = (int)(((long long)ne * b / NB) & ~3LL);
    const int hi = (b == NB - 1) ? ne : (int)(((long long)ne * (b + 1) / NB) & ~3LL);
    const int hi4 = hi & ~3;

    const int4* d4 = (const int4*)dsts;
    const int4* s4 = (const int4*)srcs;
    for (int i = lo / 4 + (int)threadIdx.x; 4 * i + 3 < hi; i += TPB) {
        int4 vd = d4[i];
        int4 vs = s4[i];
#pragma unroll
        for (int j = 0; j < 4; ++j) {
            int d = (j == 0) ? vd.x : (j == 1) ? vd.y : (j == 2) ? vd.z : vd.w;
            int s = (j == 0) ? vs.x : (j == 1) ? vs.y : (j == 2) ? vs.z : vs.w;
            int r = d >> LOG2NPR;
            unsigned p = ((unsigned)(d & (NPR - 1)) << 17) | (unsigned)s;
            int slot = atomicAdd(&cur[r], 1);
            rec[slot] = p;
        }
    }
    for (int e = hi4 + (int)threadIdx.x; e < hi; e += TPB) {   // tail
        int d = dsts[e];
        int s = srcs[e];
        int r = d >> LOG2NPR;
        unsigned p = ((unsigned)(d & (NPR - 1)) << 17) | (unsigned)s;
        int slot = atomicAdd(&cur[r], 1);
        rec[slot] = p;
    }
}

// ---- phase 2: bucket accumulation, 2 packed u64 LDS atomics per edge ----
__global__ __launch_bounds__(TPB) void accum_kernel(
    const float2* __restrict__ pos, const float2* __restrict__ vel,
    int S, const unsigned* __restrict__ rec, const int* __restrict__ meta,
    unsigned long long* __restrict__ part)
{
    __shared__ unsigned long long sm[2 * NPR];   // 128 KiB: F1 plane, F2 plane
    const int r  = blockIdx.x, si = blockIdx.y;
    const int base = meta[r];
    const int tot  = meta[MAXR + r];
    const int lo = base + (int)((long long)tot * si / S);
    const int hi = base + (int)((long long)tot * (si + 1) / S);
    const int nbase = r << LOG2NPR;

    for (int i = threadIdx.x; i < 2 * NPR; i += TPB) sm[i] = 0ull;
    __syncthreads();

    // 1-ahead prefetch of rec + pos gathers
    int i = lo + (int)threadIdx.x;
    unsigned p = 0; float2 ps = {}, pd = {};
    if (i < hi) {
        p = rec[i];
        ps = pos[p & 0x1FFFFu];
        pd = pos[nbase + (int)(p >> 17)];
    }

    for (; i < hi; i += TPB) {
        unsigned pn = 0; float2 psn = {}, pdn = {};
        if (i + TPB < hi) {
            pn = rec[i + TPB];
            psn = pos[pn & 0x1FFFFu];
            pdn = pos[nbase + (int)(pn >> 17)];
        }

        int local = (int)(p >> 17);
        float x0 = pd.x - ps.x;
        float x1 = pd.y - ps.y;

        float m0 = 0.f, m1 = 0.f, m2 = 0.f, m3 = 0.f;
        bool zmask = false;
        if (x0 == 0.0f && x1 == 0.0f) {          // rare: lazy vel check
            int s = (int)(p & 0x1FFFFu);
            float2 vs = vel[s], vd = vel[nbase + local];
            zmask = (vd.x == vs.x) && (vd.y == vs.y);
        }
        if (!zmask) compute_msgs(x0, x1, m0, m1, m2, m3);

        unsigned v0 = (unsigned)((int)rintf(m0 * MSCALE) + MBIAS);
        unsigned v1 = (unsigned)((int)rintf(m1 * MSCALE) + MBIAS);
        unsigned v2 = (unsigned)((int)rintf(m2 * MSCALE) + MBIAS);
        unsigned v3 = (unsigned)((int)rintf(m3 * MSCALE) + MBIAS);
        unsigned long long F1 = (1ULL << 46) |
                                ((unsigned long long)v2 << 23) | v3;
        unsigned long long F2 = ((unsigned long long)v0 << 23) | v1;
        atomicAdd(&sm[local], F1);
        atomicAdd(&sm[NPR + local], F2);

        p = pn; ps = psn; pd = pdn;
    }
    __syncthreads();
    unsigned long long* dst = part + (size_t)(r * S + si) * (2 * NPR);
    for (int k = threadIdx.x; k < 2 * NPR; k += TPB) dst[k] = sm[k];
}

// ---- phase 3: fold S partials, decode fixed-point, update net ----
__global__ __launch_bounds__(256) void reduce_node_kernel(
    const unsigned long long* __restrict__ part, float2* __restrict__ out,
    int n, int S)
{
    int i = blockIdx.x * blockDim.x + threadIdx.x;
    if (i >= n) return;
    int r  = i >> LOG2NPR;
    int li = i & (NPR - 1);
    unsigned long long F1 = 0ull, F2 = 0ull;
    const unsigned long long* p = part + (size_t)(r * S) * (2 * NPR) + li;
    for (int s = 0; s < S; ++s, p += 2 * NPR) {
        F1 += p[0];
        F2 += p[NPR];
    }
    float c   = (float)(F1 >> 46);
    float bia = c * (float)MBIAS;
    const float inv = 1.0f / MSCALE;
    float y0 = ((float)(unsigned)((F1 >> 23) & FMASK) - bia) * inv;  // sum m2
    float y1 = ((float)(unsigned)(F1 & FMASK)         - bia) * inv;  // sum m3
    float s0 = ((float)(unsigned)((F2 >> 23) & FMASK) - bia) * inv;  // sum m0
    float s1 = ((float)(unsigned)(F2 & FMASK)         - bia) * inv;  // sum m1
    float cm = fmaxf(c, 1.0f);
    float p0, p1;
    update_net(y0, y1, s0 / cm, s1 / cm, p0, p1);
    out[i] = make_float2(p0, p1);
}

// ---- fallback path: global atomics (proven R2) ----
__global__ __launch_bounds__(256) void zero_ws_kernel(float* __restrict__ p, int n) {
    int i = blockIdx.x * blockDim.x + threadIdx.x;
    if (i < n) p[i] = 0.0f;
}

__global__ __launch_bounds__(256) void edge_atomic_kernel(
    const float2* __restrict__ pos, const float2* __restrict__ vel,
    const int* __restrict__ ei,
    float* __restrict__ a0, float* __restrict__ a1,
    float* __restrict__ a2, float* __restrict__ a3,
    float* __restrict__ cnt, int ne)
{
    int stride = gridDim.x * blockDim.x;
    for (int e = blockIdx.x * blockDim.x + threadIdx.x; e < ne; e += stride) {
        int s = ei[e];
        int d = ei[ne + e];
        float2 ps = pos[s], pd = pos[d];
        float x0 = pd.x - ps.x, x1 = pd.y - ps.y;
        bool zmask = false;
        if (x0 == 0.0f && x1 == 0.0f) {
            float2 vs = vel[s], vd = vel[d];
            zmask = (vd.x == vs.x) && (vd.y == vs.y);
        }
        unsafeAtomicAdd(&cnt[d], 1.0f);
        if (!zmask) {
            float m0, m1, m2, m3;
            compute_msgs(x0, x1, m0, m1, m2, m3);
            unsafeAtomicAdd(&a0[d], m2);
            unsafeAtomicAdd(&a1[d], m3);
            unsafeAtomicAdd(&a2[d], m0);
            unsafeAtomicAdd(&a3[d], m1);
        }
    }
}

__global__ __launch_bounds__(256) void node_kernel(
    const float* __restrict__ a0, const float* __restrict__ a1,
    const float* __restrict__ a2, const float* __restrict__ a3,
    const float* __restrict__ cnt, float2* __restrict__ out, int n)
{
    int i = blockIdx.x * blockDim.x + threadIdx.x;
    if (i >= n) return;
    float c = fmaxf(cnt[i], 1.0f);
    float p0, p1;
    update_net(a0[i], a1[i], a2[i] / c, a3[i] / c, p0, p1);
    out[i] = make_float2(p0, p1);
}

extern "C" void kernel_launch(void* const* d_in, const int* in_sizes, int n_in,
                              void* d_out, int out_size, void* d_ws, size_t ws_size,
                              hipStream_t stream) {
    const float2* pos = (const float2*)d_in[0];
    const float2* vel = (const float2*)d_in[1];
    const int* ei = (const int*)d_in[2];
    int n  = in_sizes[0] / 2;   // 100000
    int ne = in_sizes[2] / 2;   // 6400000

    int nranges = (n + NPR - 1) / NPR;
    size_t fixed    = ((size_t)NB * MAXR * 2 + 2 * MAXR + (size_t)ne) * sizeof(int);
    fixed = (fixed + 7) & ~(size_t)7;
    size_t per_part = (size_t)nranges * 2 * NPR * sizeof(unsigned long long); // 1.66MB/slice

    int S = 0;
    if (nranges <= MAXR && n <= (1 << 17) && ws_size > fixed)
        S = (int)((ws_size - fixed) / per_part);
    if (S > 19) S = 19;                 // 13*19 = 247 blocks <= 256 CUs

    if (S >= 1) {
        int* cnts = (int*)d_ws;          // [NB][MAXR]
        int* offs = cnts + NB * MAXR;    // [NB][MAXR]
        int* meta = offs + NB * MAXR;    // base[MAXR], total[MAXR]
        unsigned* rec = (unsigned*)(meta + 2 * MAXR);   // [ne] payloads
        unsigned long long* part =
            (unsigned long long*)(((uintptr_t)d_ws + fixed + 7) & ~(uintptr_t)7);
        const int* srcs = ei;
        const int* dsts = ei + ne;

        count_kernel<<<NB, TPB, 0, stream>>>(dsts, ne, cnts);
        scan_kernel<<<1, TPB, 0, stream>>>(cnts, offs, meta, nranges);
        fill_kernel<<<NB, TPB, 0, stream>>>(srcs, dsts, ne, nranges, offs, rec);
        dim3 g(nranges, S);
        accum_kernel<<<g, TPB, 0, stream>>>(pos, vel, S, rec, meta, part);
        reduce_node_kernel<<<(n + 255) / 256, 256, 0, stream>>>(part,
                                                 (float2*)d_out, n, S);
    } else {
        float* ws = (float*)d_ws;
        float* a0  = ws;
        float* a1  = ws + n;
        float* a2  = ws + 2 * (size_t)n;
        float* a3  = ws + 3 * (size_t)n;
        float* cnt = ws + 4 * (size_t)n;
        int zeroN = 5 * n;
        zero_ws_kernel<<<(zeroN + 255) / 256, 256, 0, stream>>>(ws, zeroN);
        edge_atomic_kernel<<<(ne + 255) / 256, 256, 0, stream>>>(pos, vel, ei,
                                                a0, a1, a2, a3, cnt, ne);
        node_kernel<<<(n + 255) / 256, 256, 0, stream>>>(a0, a1, a2, a3, cnt,
                                                (float2*)d_out, n);
    }
}